// Round 2
// baseline (647.966 us; speedup 1.0000x reference)
//
#include <hip/hip_runtime.h>

// Fused tanh-RNN: h_{t+1} = tanh(x_t @ W_ih^T + b_ih + b_hh + h_t @ W_hh^T)
// out = h_T @ W_out^T + b_out.  B=4096, T=512, I=28, H=64, O=10.
// One wave (64 thr) owns 16 batch rows for all 512 steps; batch rows are
// independent -> 256 blocks x 1 wave, no inter-block communication.
//
// R2 changes vs R1 (404 us):
//  - NO __syncthreads in the loop. Single-wave block: LDS ops from one wave
//    complete in order at the LDS, so ds_write -> ds_read RAW is safe with
//    only a compiler fence. This removes the s_waitcnt vmcnt(0) drain that
//    put ~900 cyc of HBM prefetch latency on the critical path EVERY step.
//  - x prefetch 2 steps deep (slack > HBM latency once steps get short).
//  - h LDS layout [row][hidden] stride 68 dwords: reads = 4x ds_read_b128
//    (conflict-free: start banks 4c+8q tile evenly), writes = 16x b32
//    (2-way on q-pairs = free). R1's stride-20 [j][r] was 4-way on reads.
//  - bf16 hi/lo split via v_perm_b32 (1 op packs 2 floats' high halves).
//  - bias rides in as the C operand of the first MFMA (no acc init movs).

#define T_STEPS 512
#define I_DIM   28
#define H_DIM   64
#define O_DIM   10
#define ROWS    16
#define LDSS    68   // dwords per h row: 64 + 4 pad; 68*4 = 272 = 17*16 -> b128-aligned rows

typedef __attribute__((ext_vector_type(8))) short bfrag;   // 8 x bf16 (4 VGPRs)
typedef __attribute__((ext_vector_type(4))) float ffrag;   // MFMA C/D
typedef __attribute__((ext_vector_type(4))) float float4v;

#define MFMA(a,b,c) __builtin_amdgcn_mfma_f32_16x16x32_bf16((a),(b),(c),0,0,0)
#define WAVE_FENCE() asm volatile("" ::: "memory")

union FragU { bfrag s; unsigned u[4]; };

// pack bf16(f0) | bf16(f1)<<16 in one v_perm_b32 (truncation split)
__device__ __forceinline__ unsigned hi_pack(float f0, float f1){
  return __builtin_amdgcn_perm(__float_as_uint(f1), __float_as_uint(f0), 0x07060302u);
}

// fp32 -> (hi bf16, lo bf16) with v = hi + lo up to ~2^-16 rel (as R1, absmax 0.0039)
__device__ __forceinline__ void split8v(float4v a, float4v b, bfrag& hi, bfrag& lo){
  float f[8] = {a.x,a.y,a.z,a.w, b.x,b.y,b.z,b.w};
  FragU H, L;
#pragma unroll
  for (int m = 0; m < 4; m++){
    float f0 = f[2*m], f1 = f[2*m+1];
    H.u[m] = hi_pack(f0, f1);
    float l0 = f0 - __uint_as_float(__float_as_uint(f0) & 0xffff0000u);
    float l1 = f1 - __uint_as_float(__float_as_uint(f1) & 0xffff0000u);
    L.u[m] = hi_pack(l0, l1);
  }
  hi = H.s; lo = L.s;
}

__device__ __forceinline__ float fast_tanh(float p){
  // tanh(p) = 1 - 2/(exp2(2*log2e*p)+1); saturates correctly at +-large p.
  float e = __builtin_amdgcn_exp2f(p * 2.88539008177792681f);
  return __builtin_fmaf(-2.0f, __builtin_amdgcn_rcpf(e + 1.0f), 1.0f);
}

__global__ __launch_bounds__(64, 1) void rnn_fused(
    const float* __restrict__ x,
    const float* __restrict__ W_ih,
    const float* __restrict__ W_hh,
    const float* __restrict__ b_ih,
    const float* __restrict__ b_hh,
    const float* __restrict__ W_out,
    const float* __restrict__ b_out,
    float* __restrict__ out)
{
  __shared__ float hT[ROWS * LDSS];    // h row-major: hT[r*LDSS + j]
  const int lane = threadIdx.x;        // 64 threads = 1 wave
  const int c = lane & 15;
  const int q = lane >> 4;
  const int rowbase = blockIdx.x * ROWS;

  // ---- W_hh^T as B-fragments (hi/lo): B[k][n], n=c+16nt, k=32kt+8q+jj ----
  // B[k][j] = W_hh[j][k] -> 8 consecutive floats of row j=c+16nt.
  bfrag whh_hi[4][2], whh_lo[4][2];
#pragma unroll
  for (int nt = 0; nt < 4; ++nt)
#pragma unroll
    for (int kt = 0; kt < 2; ++kt){
      const float* p = W_hh + (c + 16*nt)*H_DIM + kt*32 + q*8;
      split8v(*(const float4v*)p, *(const float4v*)(p + 4),
              whh_hi[nt][kt], whh_lo[nt][kt]);
    }

  // ---- W_ih^T as B-fragments, K padded 28 -> 32 with zeros ----
  bfrag wih_hi[4], wih_lo[4];
#pragma unroll
  for (int nt = 0; nt < 4; ++nt){
    const float* p = W_ih + (c + 16*nt)*I_DIM + q*8;
    float4v a = *(const float4v*)p;                       // i <= 27: always valid
    float4v b;
    if (q < 3) b = *(const float4v*)(p + 4);
    else       b = (float4v){0.f, 0.f, 0.f, 0.f};          // i = 28..31 pad
    split8v(a, b, wih_hi[nt], wih_lo[nt]);
  }

  // bias as a C-operand fragment: col j = c+16nt, same for all 4 rows/regs
  ffrag biasf[4];
#pragma unroll
  for (int nt = 0; nt < 4; ++nt){
    float bb = b_ih[c + 16*nt] + b_hh[c + 16*nt];
    biasf[nt].x = bb; biasf[nt].y = bb; biasf[nt].z = bb; biasf[nt].w = bb;
  }

  // ---- h state A-fragments (hi/lo), h0 = 0 ----
  bfrag h_hi[2], h_lo[2];
#pragma unroll
  for (int kt = 0; kt < 2; ++kt){
    FragU Z; Z.u[0]=Z.u[1]=Z.u[2]=Z.u[3]=0;
    h_hi[kt] = Z.s; h_lo[kt] = Z.s;
  }

  // ---- x pipeline, 2 steps deep. A-frag pattern: row r=c, i=q*8+jj. ----
  // quad 3's upper 4 floats multiply zero W pad -> clamp pointer, value is don't-care.
  const float* xbase = x + ((size_t)(rowbase + c) * T_STEPS) * I_DIM;
  const float* xp2 = xbase;                      // points at most recently loaded step
  float4v xa0 = *(const float4v*)xp2;
  float4v xb0 = *(const float4v*)(q < 3 ? xp2 + q*8 + 4 : xp2 + q*8);
  xa0 = *(const float4v*)(xp2 + q*8);
  xp2 = xbase + I_DIM;                           // t = 1
  float4v xa1 = *(const float4v*)(xp2 + q*8);
  float4v xb1 = *(const float4v*)(q < 3 ? xp2 + q*8 + 4 : xp2 + q*8);

  for (int t = 0; t < T_STEPS; ++t){
    // 1) issue prefetch for t+2 (clamped); first use is 2 steps away
    const float* xn = (t < T_STEPS - 2) ? (xp2 + I_DIM) : xp2;
    float4v na = *(const float4v*)(xn + q*8);
    float4v nb = *(const float4v*)(q < 3 ? xn + q*8 + 4 : xn + q*8);

    // 2) split current x (loaded 2 steps ago -> no wait)
    bfrag xhi, xlo;
    split8v(xa0, xb0, xhi, xlo);

    // 3) input projection, bias as C; nt-interleaved so dep chains are 4 apart
    ffrag acc[4];
#pragma unroll
    for (int nt = 0; nt < 4; ++nt) acc[nt] = MFMA(xhi, wih_hi[nt], biasf[nt]);
#pragma unroll
    for (int nt = 0; nt < 4; ++nt) acc[nt] = MFMA(xlo, wih_hi[nt], acc[nt]);
#pragma unroll
    for (int nt = 0; nt < 4; ++nt) acc[nt] = MFMA(xhi, wih_lo[nt], acc[nt]);

    // 4) recurrence (bf16x3), nt-innermost interleave
#pragma unroll
    for (int kt = 0; kt < 2; ++kt){
#pragma unroll
      for (int nt = 0; nt < 4; ++nt) acc[nt] = MFMA(h_hi[kt], whh_hi[nt][kt], acc[nt]);
#pragma unroll
      for (int nt = 0; nt < 4; ++nt) acc[nt] = MFMA(h_lo[kt], whh_hi[nt][kt], acc[nt]);
#pragma unroll
      for (int nt = 0; nt < 4; ++nt) acc[nt] = MFMA(h_hi[kt], whh_lo[nt][kt], acc[nt]);
    }

    // 5) tanh + transposed store. C-layout: lane holds rows q*4+reg, col c+16nt.
    //    Store into hT[r][j]: 16 scalar b32, banks (16q + 20reg + c) -> 2-way, free.
    //    No barrier: single wave, LDS ops complete in order.
    WAVE_FENCE();
#pragma unroll
    for (int nt = 0; nt < 4; ++nt){
      int wb = (q*4)*LDSS + c + 16*nt;
      hT[wb         ] = fast_tanh(acc[nt].x);
      hT[wb +   LDSS] = fast_tanh(acc[nt].y);
      hT[wb + 2*LDSS] = fast_tanh(acc[nt].z);
      hT[wb + 3*LDSS] = fast_tanh(acc[nt].w);
    }
    WAVE_FENCE();

    // 6) reload h as A-frags: lane (c,q) reads h[c][kt*32+q*8 .. +7], b128 x2,
    //    conflict-free; then perm-pack hi/lo.
#pragma unroll
    for (int kt = 0; kt < 2; ++kt){
      const float* rp = &hT[c*LDSS + kt*32 + q*8];
      float4v ra = *(const float4v*)rp;
      float4v rb = *(const float4v*)(rp + 4);
      split8v(ra, rb, h_hi[kt], h_lo[kt]);
    }
    WAVE_FENCE();

    // 7) rotate x pipeline
    xa0 = xa1; xb0 = xb1;
    xa1 = na;  xb1 = nb;
    xp2 = xn;
  }

  // epilogue: out[r][o] = b_out[o] + sum_k h[r][k] * W_out[o][k]; r=c, o strided by q
  for (int oo = q; oo < O_DIM; oo += 4){
    float s = b_out[oo];
#pragma unroll 8
    for (int k = 0; k < H_DIM; ++k)
      s += hT[c*LDSS + k] * W_out[oo*H_DIM + k];
    out[(size_t)(rowbase + c)*O_DIM + oo] = s;
  }
}

extern "C" void kernel_launch(void* const* d_in, const int* in_sizes, int n_in,
                              void* d_out, int out_size, void* d_ws, size_t ws_size,
                              hipStream_t stream) {
  const float* x     = (const float*)d_in[0];
  const float* W_ih  = (const float*)d_in[1];
  const float* W_hh  = (const float*)d_in[2];
  const float* b_ih  = (const float*)d_in[3];
  const float* b_hh  = (const float*)d_in[4];
  const float* W_out = (const float*)d_in[5];
  const float* b_out = (const float*)d_in[6];
  float* out = (float*)d_out;

  int B = in_sizes[0] / (T_STEPS * I_DIM);   // 4096
  rnn_fused<<<B / ROWS, 64, 0, stream>>>(x, W_ih, W_hh, b_ih, b_hh, W_out, b_out, out);
}

// Round 3
// 645.998 us; speedup vs baseline: 1.0030x; 1.0030x over previous
//
#include <hip/hip_runtime.h>

// Fused tanh-RNN: h_{t+1} = tanh(x_t @ W_ih^T + b_ih + b_hh + h_t @ W_hh^T)
// out = h_T @ W_out^T + b_out.  B=4096, T=512, I=28, H=64, O=10.
// One wave (64 thr) owns 16 batch rows for all 512 steps; 256 blocks x 1 wave.
// Kernel time = 512 x per-step critical chain (serial in t), so R3 attacks
// the chain itself:
//  - T-loop unrolled 4x with a 4-slot x register pipeline: each body consumes
//    slot s and reloads the SAME slot for t+4. Static renaming -> no v_movs
//    from in-flight load registers -> no forced vmcnt drain on the chain
//    (R1/R2's ~900 cyc/step stall; R1 barrier vs R2 rotation timed identical).
//  - MFMA dependency depth from h-ready cut 9 -> 3: two acc chains per nt
//    (kt=0 chains on the x-projection acc, kt=1 on a const-zero-C acc),
//    merged by one v_add per element. x-proj MFMAs are off the h-path.
//  - bf16x3 operand split (hi/lo) everywhere: absmax 0.0039 vs thr 0.0255.
//  - Single-wave block: no barriers; same-wave LDS ordering (validated R2).

#define T_STEPS 512
#define I_DIM   28
#define H_DIM   64
#define O_DIM   10
#define ROWS    16
#define LDSS    68   // dwords per h row; 68*4B rows are b128-aligned; reads conflict-free

typedef __attribute__((ext_vector_type(8))) short bfrag;   // 8 x bf16 (4 VGPRs)
typedef __attribute__((ext_vector_type(4))) float ffrag;   // MFMA C/D
typedef __attribute__((ext_vector_type(4))) float float4v;

#define MFMA(a,b,c) __builtin_amdgcn_mfma_f32_16x16x32_bf16((a),(b),(c),0,0,0)
#define WAVE_FENCE() asm volatile("" ::: "memory")

union FragU { bfrag s; unsigned u[4]; };

// pack bf16(f0) | bf16(f1)<<16 in one v_perm_b32 (truncation split)
__device__ __forceinline__ unsigned hi_pack(float f0, float f1){
  return __builtin_amdgcn_perm(__float_as_uint(f1), __float_as_uint(f0), 0x07060302u);
}

// fp32 -> (hi bf16, lo bf16), v = hi + lo up to ~2^-16 rel
__device__ __forceinline__ void split8v(float4v a, float4v b, bfrag& hi, bfrag& lo){
  float f[8] = {a.x,a.y,a.z,a.w, b.x,b.y,b.z,b.w};
  FragU H, L;
#pragma unroll
  for (int m = 0; m < 4; m++){
    float f0 = f[2*m], f1 = f[2*m+1];
    H.u[m] = hi_pack(f0, f1);
    float l0 = f0 - __uint_as_float(__float_as_uint(f0) & 0xffff0000u);
    float l1 = f1 - __uint_as_float(__float_as_uint(f1) & 0xffff0000u);
    L.u[m] = hi_pack(l0, l1);
  }
  hi = H.s; lo = L.s;
}

__device__ __forceinline__ float fast_tanh(float p){
  // tanh(p) = 1 - 2/(exp2(2*log2e*p)+1); saturates correctly for large |p|.
  float e = __builtin_amdgcn_exp2f(p * 2.88539008177792681f);
  return __builtin_fmaf(-2.0f, __builtin_amdgcn_rcpf(e + 1.0f), 1.0f);
}

// One RNN step. T_C: step index (uniform). XA/XB: this step's x regs (consumed,
// then overwritten by the t+4 load -> 4-deep pipeline with no rotation movs).
// HIN/HOUT: ping-pong h fragment names.
#define BODY(T_C, XA, XB, HIN_HI, HIN_LO, HOUT_HI, HOUT_LO)                    \
  {                                                                            \
    bfrag xhi, xlo;                                                            \
    split8v(XA, XB, xhi, xlo);                                                 \
    {                                                                          \
      int tload = (T_C) + 4; if (tload > T_STEPS - 1) tload = T_STEPS - 1;     \
      const float* lp = xrow + (size_t)tload * I_DIM;                          \
      XA = *(const float4v*)lp;                                                \
      XB = *(const float4v*)(qlt3 ? lp + 4 : lp);                              \
    }                                                                          \
    ffrag acA[4], acB[4];                                                      \
    _Pragma("unroll")                                                          \
    for (int nt = 0; nt < 4; ++nt) acA[nt] = MFMA(xhi, wih_hi[nt], biasf[nt]); \
    _Pragma("unroll")                                                          \
    for (int nt = 0; nt < 4; ++nt) acB[nt] = MFMA(xhi, wih_lo[nt], zfrag);     \
    _Pragma("unroll")                                                          \
    for (int nt = 0; nt < 4; ++nt) acA[nt] = MFMA(xlo, wih_hi[nt], acA[nt]);   \
    /* h chains: 8 independent chains (acA/acB x 4nt), depth 3 from h-ready */ \
    _Pragma("unroll")                                                          \
    for (int nt = 0; nt < 4; ++nt) acA[nt] = MFMA(HIN_HI[0], whh_hi[nt][0], acA[nt]); \
    _Pragma("unroll")                                                          \
    for (int nt = 0; nt < 4; ++nt) acB[nt] = MFMA(HIN_HI[1], whh_hi[nt][1], acB[nt]); \
    _Pragma("unroll")                                                          \
    for (int nt = 0; nt < 4; ++nt) acA[nt] = MFMA(HIN_LO[0], whh_hi[nt][0], acA[nt]); \
    _Pragma("unroll")                                                          \
    for (int nt = 0; nt < 4; ++nt) acB[nt] = MFMA(HIN_LO[1], whh_hi[nt][1], acB[nt]); \
    _Pragma("unroll")                                                          \
    for (int nt = 0; nt < 4; ++nt) acA[nt] = MFMA(HIN_HI[0], whh_lo[nt][0], acA[nt]); \
    _Pragma("unroll")                                                          \
    for (int nt = 0; nt < 4; ++nt) acB[nt] = MFMA(HIN_HI[1], whh_lo[nt][1], acB[nt]); \
    WAVE_FENCE();                                                              \
    _Pragma("unroll")                                                          \
    for (int nt = 0; nt < 4; ++nt){                                            \
      int wb = (q*4)*LDSS + c + 16*nt;                                         \
      hT[wb         ] = fast_tanh(acA[nt].x + acB[nt].x);                      \
      hT[wb +   LDSS] = fast_tanh(acA[nt].y + acB[nt].y);                      \
      hT[wb + 2*LDSS] = fast_tanh(acA[nt].z + acB[nt].z);                      \
      hT[wb + 3*LDSS] = fast_tanh(acA[nt].w + acB[nt].w);                      \
    }                                                                          \
    WAVE_FENCE();                                                              \
    _Pragma("unroll")                                                          \
    for (int kt = 0; kt < 2; ++kt){                                            \
      const float* rp = &hT[c*LDSS + kt*32 + q*8];                             \
      split8v(*(const float4v*)rp, *(const float4v*)(rp + 4),                  \
              HOUT_HI[kt], HOUT_LO[kt]);                                       \
    }                                                                          \
    WAVE_FENCE();                                                              \
  }

__global__ __launch_bounds__(64, 1) void rnn_fused(
    const float* __restrict__ x,
    const float* __restrict__ W_ih,
    const float* __restrict__ W_hh,
    const float* __restrict__ b_ih,
    const float* __restrict__ b_hh,
    const float* __restrict__ W_out,
    const float* __restrict__ b_out,
    float* __restrict__ out)
{
  __shared__ float hT[ROWS * LDSS];    // h row-major: hT[r*LDSS + j]
  const int lane = threadIdx.x;        // 64 threads = 1 wave
  const int c = lane & 15;
  const int q = lane >> 4;
  const bool qlt3 = (q < 3);
  const int rowbase = blockIdx.x * ROWS;

  // ---- W_hh^T as B-fragments (hi/lo): B[k][n], n=c+16nt, k=32kt+8q+jj ----
  bfrag whh_hi[4][2], whh_lo[4][2];
#pragma unroll
  for (int nt = 0; nt < 4; ++nt)
#pragma unroll
    for (int kt = 0; kt < 2; ++kt){
      const float* p = W_hh + (c + 16*nt)*H_DIM + kt*32 + q*8;
      split8v(*(const float4v*)p, *(const float4v*)(p + 4),
              whh_hi[nt][kt], whh_lo[nt][kt]);
    }

  // ---- W_ih^T as B-fragments, K padded 28 -> 32 with zeros ----
  bfrag wih_hi[4], wih_lo[4];
#pragma unroll
  for (int nt = 0; nt < 4; ++nt){
    const float* p = W_ih + (c + 16*nt)*I_DIM + q*8;
    float4v a = *(const float4v*)p;                        // i <= 27: in-bounds
    float4v b;
    if (qlt3) b = *(const float4v*)(p + 4);
    else      b = (float4v){0.f, 0.f, 0.f, 0.f};           // i = 28..31 pad
    split8v(a, b, wih_hi[nt], wih_lo[nt]);
  }

  // bias as C-operand fragment; const zero fragment for the second acc chain
  ffrag biasf[4];
#pragma unroll
  for (int nt = 0; nt < 4; ++nt){
    float bb = b_ih[c + 16*nt] + b_hh[c + 16*nt];
    biasf[nt].x = bb; biasf[nt].y = bb; biasf[nt].z = bb; biasf[nt].w = bb;
  }
  const ffrag zfrag = {0.f, 0.f, 0.f, 0.f};   // never written -> no per-step init

  // ---- h ping-pong fragments, h0 = 0 ----
  bfrag hA_hi[2], hA_lo[2], hB_hi[2], hB_lo[2];
#pragma unroll
  for (int kt = 0; kt < 2; ++kt){
    FragU Z; Z.u[0]=Z.u[1]=Z.u[2]=Z.u[3]=0;
    hA_hi[kt] = Z.s; hA_lo[kt] = Z.s;
    hB_hi[kt] = Z.s; hB_lo[kt] = Z.s;
  }

  // ---- 4-slot x pipeline. A-frag pattern: row r=c, i=q*8+jj; quad 3's upper
  // float4 multiplies zero W pad -> clamp pointer (in-bounds, value don't-care).
  const float* xrow = x + ((size_t)(rowbase + c) * T_STEPS) * I_DIM + q*8;
  float4v xa[4], xb[4];
#pragma unroll
  for (int s = 0; s < 4; ++s){
    const float* p = xrow + (size_t)s * I_DIM;
    xa[s] = *(const float4v*)p;
    xb[s] = *(const float4v*)(qlt3 ? p + 4 : p);
  }

#pragma unroll 1
  for (int tb = 0; tb < T_STEPS; tb += 4){
    BODY(tb + 0, xa[0], xb[0], hA_hi, hA_lo, hB_hi, hB_lo);
    BODY(tb + 1, xa[1], xb[1], hB_hi, hB_lo, hA_hi, hA_lo);
    BODY(tb + 2, xa[2], xb[2], hA_hi, hA_lo, hB_hi, hB_lo);
    BODY(tb + 3, xa[3], xb[3], hB_hi, hB_lo, hA_hi, hA_lo);
  }

  // epilogue: out[r][o] = b_out[o] + sum_k h[r][k] * W_out[o][k]; r=c
  for (int oo = q; oo < O_DIM; oo += 4){
    float s = b_out[oo];
#pragma unroll 8
    for (int k = 0; k < H_DIM; ++k)
      s += hT[c*LDSS + k] * W_out[oo*H_DIM + k];
    out[(size_t)(rowbase + c)*O_DIM + oo] = s;
  }
}

extern "C" void kernel_launch(void* const* d_in, const int* in_sizes, int n_in,
                              void* d_out, int out_size, void* d_ws, size_t ws_size,
                              hipStream_t stream) {
  const float* x     = (const float*)d_in[0];
  const float* W_ih  = (const float*)d_in[1];
  const float* W_hh  = (const float*)d_in[2];
  const float* b_ih  = (const float*)d_in[3];
  const float* b_hh  = (const float*)d_in[4];
  const float* W_out = (const float*)d_in[5];
  const float* b_out = (const float*)d_in[6];
  float* out = (float*)d_out;

  int B = in_sizes[0] / (T_STEPS * I_DIM);   // 4096
  rnn_fused<<<B / ROWS, 64, 0, stream>>>(x, W_ih, W_hh, b_ih, b_hh, W_out, b_out, out);
}

// Round 4
// 459.738 us; speedup vs baseline: 1.4094x; 1.4051x over previous
//
#include <hip/hip_runtime.h>

// Fused tanh-RNN: h_{t+1} = tanh(x_t @ W_ih^T + b_ih + b_hh + h_t @ W_hh^T)
// out = h_T @ W_out^T + b_out.  B=4096, T=512, I=28, H=64, O=10.
//
// R4: N-SPLIT ACROSS 4 WAVES. R1-R3 (404/416/437 us) proved the per-step cost
// is one wave's serial issue + latency with nothing to overlap (1 wave/CU).
// Batch-splitting can't shorten the serial t-chain; splitting the STEP's work
// can: 4 waves/block on 4 SIMDs, wave w computes hidden cols [16w,16w+16) for
// the block's 16 batch rows. Per wave per step: 9 MFMAs, 4 tanh (8 trans ops),
// ~60 VALU — a 4x cut of every issue component. Chain depth unchanged.
// h is exchanged through double-buffered LDS with a hand-rolled barrier that
// drains ONLY lgkmcnt (LDS) — NOT vmcnt — so the 4-slot x register prefetch
// stays in flight across the barrier (R1 showed __syncthreads' vmcnt(0) drain
// costs ~900 cyc/step).
// bf16x3 split (hi+lo operands) keeps absmax at 0.0039 vs threshold 0.0255.

#define T_STEPS 512
#define I_DIM   28
#define H_DIM   64
#define O_DIM   10
#define ROWS    16
#define LDSS    68            // dwords per h row; rows 16B-aligned, reads conflict-free
#define HBUF    (ROWS * LDSS)

typedef __attribute__((ext_vector_type(8))) short bfrag;   // 8 x bf16 (4 VGPRs)
typedef __attribute__((ext_vector_type(4))) float ffrag;   // MFMA C/D
typedef __attribute__((ext_vector_type(4))) float float4v;

#define MFMA(a,b,c) __builtin_amdgcn_mfma_f32_16x16x32_bf16((a),(b),(c),0,0,0)
// Workgroup barrier draining ONLY LDS ops. Inter-wave deps are LDS-only here,
// so global (vmcnt) loads legally stay outstanding across it.
#define LDS_BARRIER() asm volatile("s_waitcnt lgkmcnt(0)\n\ts_barrier" ::: "memory")

union FragU { bfrag s; unsigned u[4]; };

// pack bf16(f0) | bf16(f1)<<16 in one v_perm_b32 (truncation split)
__device__ __forceinline__ unsigned hi_pack(float f0, float f1){
  return __builtin_amdgcn_perm(__float_as_uint(f1), __float_as_uint(f0), 0x07060302u);
}

// fp32 -> (hi bf16, lo bf16), v = hi + lo up to ~2^-16 rel
__device__ __forceinline__ void split8v(float4v a, float4v b, bfrag& hi, bfrag& lo){
  float f[8] = {a.x,a.y,a.z,a.w, b.x,b.y,b.z,b.w};
  FragU H, L;
#pragma unroll
  for (int m = 0; m < 4; m++){
    float f0 = f[2*m], f1 = f[2*m+1];
    H.u[m] = hi_pack(f0, f1);
    float l0 = f0 - __uint_as_float(__float_as_uint(f0) & 0xffff0000u);
    float l1 = f1 - __uint_as_float(__float_as_uint(f1) & 0xffff0000u);
    L.u[m] = hi_pack(l0, l1);
  }
  hi = H.s; lo = L.s;
}

__device__ __forceinline__ float fast_tanh(float p){
  // tanh(p) = 1 - 2/(exp2(2*log2e*p)+1); saturates correctly for large |p|.
  float e = __builtin_amdgcn_exp2f(p * 2.88539008177792681f);
  return __builtin_fmaf(-2.0f, __builtin_amdgcn_rcpf(e + 1.0f), 1.0f);
}

// One RNN step for one wave (its 16 hidden cols). XA/XB are this step's x regs:
// consumed, then overwritten with the t+4 load (static renaming, no movs).
// BUF_OFF selects the h double-buffer half being WRITTEN (= read back for t+1):
// even T_C -> HBUF, odd T_C -> 0 (compile-time constant at each expansion).
#define BODY(T_C, XA, XB, BUF_OFF)                                             \
  {                                                                            \
    bfrag xhi, xlo;                                                            \
    split8v(XA, XB, xhi, xlo);                                                 \
    {                                                                          \
      int tload = (T_C) + 4; if (tload > T_STEPS - 1) tload = T_STEPS - 1;     \
      const float* lp = xrow + (size_t)tload * I_DIM;                          \
      XA = *(const float4v*)lp;                                                \
      XB = *(const float4v*)(qlt3 ? lp + 4 : lp);                              \
    }                                                                          \
    ffrag acA, acB;                                                            \
    /* x projection (off the h critical path; x ready 4 steps early) */        \
    acA = MFMA(xhi, wih_hi, biasf);                                            \
    acB = MFMA(xhi, wih_lo, zfrag);                                            \
    acA = MFMA(xlo, wih_hi, acA);                                              \
    /* h recurrence: 2 chains, depth 3 from h-ready */                         \
    acA = MFMA(h_hi[0], whh_hi[0], acA);                                       \
    acB = MFMA(h_hi[1], whh_hi[1], acB);                                       \
    acA = MFMA(h_lo[0], whh_hi[0], acA);                                       \
    acB = MFMA(h_lo[1], whh_hi[1], acB);                                       \
    acA = MFMA(h_hi[0], whh_lo[0], acA);                                       \
    acB = MFMA(h_hi[1], whh_lo[1], acB);                                       \
    /* tanh + store this wave's 16 cols: rows q*4+reg, col c+16w */            \
    float* wb = hTb + (BUF_OFF) + (q*4)*LDSS + c + 16*w;                       \
    wb[0*LDSS] = fast_tanh(acA.x + acB.x);                                     \
    wb[1*LDSS] = fast_tanh(acA.y + acB.y);                                     \
    wb[2*LDSS] = fast_tanh(acA.z + acB.z);                                     \
    wb[3*LDSS] = fast_tanh(acA.w + acB.w);                                     \
    LDS_BARRIER();                                                             \
    /* reload FULL h(t+1) as A-frags: lane (c,q) reads h[c][kt*32+q*8..+7] */  \
    const float* rb = hTb + (BUF_OFF) + c*LDSS + q*8;                          \
    split8v(*(const float4v*)rb,        *(const float4v*)(rb + 4),             \
            h_hi[0], h_lo[0]);                                                 \
    split8v(*(const float4v*)(rb + 32), *(const float4v*)(rb + 36),            \
            h_hi[1], h_lo[1]);                                                 \
  }

__global__ __launch_bounds__(256, 1) void rnn_fused(
    const float* __restrict__ x,
    const float* __restrict__ W_ih,
    const float* __restrict__ W_hh,
    const float* __restrict__ b_ih,
    const float* __restrict__ b_hh,
    const float* __restrict__ W_out,
    const float* __restrict__ b_out,
    float* __restrict__ out)
{
  __shared__ float hTb[2 * HBUF];      // double-buffered h, row-major [r][j]
  const int tid  = threadIdx.x;
  const int w    = tid >> 6;           // wave id = hidden col tile (nt)
  const int lane = tid & 63;
  const int c    = lane & 15;
  const int q    = lane >> 4;
  const bool qlt3 = (q < 3);
  const int rowbase = blockIdx.x * ROWS;

  // ---- this wave's W_hh^T B-fragments (hi/lo): cols c+16w, k=32kt+8q+jj ----
  bfrag whh_hi[2], whh_lo[2];
#pragma unroll
  for (int kt = 0; kt < 2; ++kt){
    const float* p = W_hh + (c + 16*w)*H_DIM + kt*32 + q*8;
    split8v(*(const float4v*)p, *(const float4v*)(p + 4), whh_hi[kt], whh_lo[kt]);
  }

  // ---- this wave's W_ih^T B-fragment, K padded 28 -> 32 with zeros ----
  bfrag wih_hi, wih_lo;
  {
    const float* p = W_ih + (c + 16*w)*I_DIM + q*8;
    float4v a = *(const float4v*)p;                        // i <= 27: in-bounds
    float4v b;
    if (qlt3) b = *(const float4v*)(p + 4);
    else      b = (float4v){0.f, 0.f, 0.f, 0.f};           // i = 28..31 pad
    split8v(a, b, wih_hi, wih_lo);
  }

  // bias as C operand; const-zero C for the second chain
  ffrag biasf;
  {
    float bb = b_ih[c + 16*w] + b_hh[c + 16*w];
    biasf.x = bb; biasf.y = bb; biasf.z = bb; biasf.w = bb;
  }
  const ffrag zfrag = {0.f, 0.f, 0.f, 0.f};

  // h fragments (full h as A operand), h0 = 0
  bfrag h_hi[2], h_lo[2];
  {
    FragU Z; Z.u[0]=Z.u[1]=Z.u[2]=Z.u[3]=0;
    h_hi[0] = Z.s; h_lo[0] = Z.s; h_hi[1] = Z.s; h_lo[1] = Z.s;
  }

  // ---- 4-slot x pipeline (all 4 waves load the same rows; L1 dedupes).
  // A-frag pattern: row r=c, i=q*8+jj; quad 3's upper float4 multiplies zero
  // W pad -> clamp pointer (in-bounds, value don't-care).
  const float* xrow = x + ((size_t)(rowbase + c) * T_STEPS) * I_DIM + q*8;
  float4v xa[4], xb[4];
#pragma unroll
  for (int s = 0; s < 4; ++s){
    const float* p = xrow + (size_t)s * I_DIM;
    xa[s] = *(const float4v*)p;
    xb[s] = *(const float4v*)(qlt3 ? p + 4 : p);
  }

#pragma unroll 1
  for (int tb = 0; tb < T_STEPS; tb += 4){
    BODY(tb + 0, xa[0], xb[0], HBUF);   // writes h(t+1), t even -> buf 1
    BODY(tb + 1, xa[1], xb[1], 0);      // t odd  -> buf 0
    BODY(tb + 2, xa[2], xb[2], HBUF);
    BODY(tb + 3, xa[3], xb[3], 0);
  }

  // epilogue: h_512 is in buffer 0 (t=511 wrote BUF_OFF=0); wave 0 computes
  // out[r][o] = b_out[o] + sum_k h[r][k] * W_out[o][k], r=c, o strided by q.
  if (w == 0){
    for (int oo = q; oo < O_DIM; oo += 4){
      float s = b_out[oo];
#pragma unroll 8
      for (int k = 0; k < H_DIM; ++k)
        s += hTb[c*LDSS + k] * W_out[oo*H_DIM + k];
      out[(size_t)(rowbase + c)*O_DIM + oo] = s;
    }
  }
}

extern "C" void kernel_launch(void* const* d_in, const int* in_sizes, int n_in,
                              void* d_out, int out_size, void* d_ws, size_t ws_size,
                              hipStream_t stream) {
  const float* x     = (const float*)d_in[0];
  const float* W_ih  = (const float*)d_in[1];
  const float* W_hh  = (const float*)d_in[2];
  const float* b_ih  = (const float*)d_in[3];
  const float* b_hh  = (const float*)d_in[4];
  const float* W_out = (const float*)d_in[5];
  const float* b_out = (const float*)d_in[6];
  float* out = (float*)d_out;

  int B = in_sizes[0] / (T_STEPS * I_DIM);   // 4096
  rnn_fused<<<B / ROWS, 256, 0, stream>>>(x, W_ih, W_hh, b_ih, b_hh, W_out, b_out, out);
}